// Round 4
// baseline (153.746 us; speedup 1.0000x reference)
//
#include <hip/hip_runtime.h>

// Problem constants (fixed in the reference file)
#define OHh   60
#define OWw   60
#define NBINS (OHh * OWw)   // 3600
#define NB    64            // batches
#define NS    4096          // spikes per batch
#define CAP   128

#define NW     4            // waves per block
#define SEG    (NS / NW)    // 1024 spikes scanned per wave
#define CH     (SEG / 64)   // 16 chunks per wave
#define WSLOTS 40           // staged slots per wave-segment per bin (+1 dummy row)
#define PRE0   64           // slots [PRE0, CAP) prefilled -1 during scan
                            // (per-bin total ~ Poisson(25); P(>64) ~ 1e-11)

// One 4-wave block per (batch, output row); lane == ow (lanes 60..63 parked).
// R12: R10/R11 write-alignment experiments were identical (53.3 vs 53.0 us
// kernel) -> write drain is NOT the limiter; R8's scan (~25 us, LDS/SALU
// bound per R7 PMC) is. R12 keeps the R8 structure byte-for-byte but
// replaces the hitbuf LDS broadcast with the fallback path's proven
// s_ff1 + v_readlane broadcast: the hit payload moves lane->SGPR with no
// LDS traffic, and all per-hit decode (w, ckk_base) becomes scalar math
// that dual-issues with VALU. Removes per wave: 80 ds_read_u16 +
// 16 hitbuf writes + 16 mbcnt/pack sequences. s-order: ctz ascends in
// lane order == s order within a chunk, chunks in order. Dump, prefill
// pacing, fallback, grid unchanged from the proven 148.9 us kernel.
__global__ __launch_bounds__(256) void sort_spikes_row4(
    const int* __restrict__ spikes, int* __restrict__ out) {
    const int bid  = (int)blockIdx.x;
    const int b    = bid & (NB - 1);   // batch-minor -> batch b pinned to XCD b%8
    const int row  = bid >> 6;         // output row oh, 0..59
    const int tid  = (int)threadIdx.x;
    const int wv   = tid >> 6;
    const int lane = tid & 63;
    const bool valid  = lane < OWw;
    const int  lane_c = valid ? lane : 127;  // parked lanes: window test auto-fails

    __shared__ short stage[NW][WSLOTS + 1][64];  // 20992 B (+1 dummy sink)
    __shared__ int   cnt[NW][64];                // 1024 B
    __shared__ int   ovf;                        // ~21.5 KB -> 7 blocks/CU

    if (tid == 0) ovf = 0;

    const int* __restrict__ sp   = spikes + b * NS + wv * SEG;
    int* __restrict__       outb = out + (size_t)b * (CAP * NBINS) + row * OWw;

    // Issue all 16 chunk loads up front (deep vmcnt pipeline; L2-resident
    // after the first of a batch's 60 blocks touches them).
    int vs[CH];
#pragma unroll
    for (int c = 0; c < CH; ++c) vs[c] = sp[c * 64 + lane];

    short* const stage_lane  = &stage[wv][0][lane];      // + count*64 shorts
    short* const stage_dummy = &stage[wv][WSLOTS][lane]; // sink row

    int count = 0;
#pragma unroll
    for (int c = 0; c < CH; ++c) {
        const int v  = vs[c];
        const int kh = ((v >> 6) & 63) - row;
        unsigned long long mask = __ballot((unsigned)kh < 5u);  // wave-uniform

        // Hidden write: one -1 slot-row per chunk -> slots [64,128) done by
        // scan end (wv*CH+c spans 0..63). Contiguous 240 B run, paced under scan.
        if (valid) outb[(PRE0 + wv * CH + c) * NBINS + lane] = -1;

        while (mask) {                           // uniform trip count (~5/chunk)
            const int j = (int)__builtin_ctzll(mask);   // ascending = s order
            mask &= mask - 1;
            const int vj = __builtin_amdgcn_readlane(
                v, __builtin_amdgcn_readfirstlane(j));  // hit payload -> SGPR
            // Scalar decode (dual-issues with VALU):
            const int wj = vj & 63;
            const int Aj = (vj >> 12) * 25 + (((vj >> 6) & 63) - row) * 5 + wj;
            // Per-lane window test:
            const int  kw    = wj - lane_c;      // v_sub (sgpr - vgpr)
            const bool inwin = (unsigned)kw < 5u;
            const int  val   = Aj - lane_c;      // == ckk when inwin
            short* a = (inwin & (count < WSLOTS))
                           ? (stage_lane + count * 64)   // count*128 B
                           : stage_dummy;
            *a = (short)val;                     // garbage to sink is fine
            count += inwin;
        }
    }
    cnt[wv][lane] = count;
    if (__ballot(count > WSLOTS) && lane == 0) ovf = 1;  // benign multi-write
    __syncthreads();

    if (ovf == 0) {
        if (valid) {
            const int c0 = cnt[0][lane], c1 = cnt[1][lane];
            const int c2 = cnt[2][lane], c3 = cnt[3][lane];
            const int o1 = c0, o2 = c0 + c1, o3 = o2 + c2;
            const int total = o3 + c3;                 // <=160
            // Dump slots [0,64): 16 per wave, wave order == s order.
#pragma unroll 4
            for (int i = 0; i < PRE0 / NW; ++i) {
                const int k = wv * (PRE0 / NW) + i;
                int val = -1;
                if (k < total) {
                    int wsel = 0, base = 0;
                    if (k >= o1) { wsel = 1; base = o1; }
                    if (k >= o2) { wsel = 2; base = o2; }
                    if (k >= o3) { wsel = 3; base = o3; }
                    val = (int)stage[wsel][k - base][lane];  // bank=lane>>1, free
                }
                outb[k * NBINS + lane] = val;          // contiguous 240 B run
            }
            // Astronomically rare: overwrite prefilled -1s with real values.
            for (int k = PRE0 + wv; k < total && k < CAP; k += NW) {
                int wsel = 0, base = 0;
                if (k >= o1) { wsel = 1; base = o1; }
                if (k >= o2) { wsel = 2; base = o2; }
                if (k >= o3) { wsel = 3; base = o3; }
                outb[k * NBINS + lane] = (int)stage[wsel][k - base][lane];
            }
        }
    } else if (wv == 0) {
        // Fallback: >40 staged hits in one bin from one 1024-spike segment
        // (P ~ 1e-22 random input). Serial redo, direct global stores.
        const int* __restrict__ spf = spikes + b * NS;
        int cc = 0;
        for (int c = 0; c < NS / 64; ++c) {
            const int v = spf[c * 64 + lane];
            const int h = (v >> 6) & 63;
            unsigned long long mask = __ballot((unsigned)(h - row) < 5u);
            while (mask) {
                const int j = (int)__builtin_ctzll(mask);
                mask &= mask - 1;
                const int vj =
                    __builtin_amdgcn_readlane(v, __builtin_amdgcn_readfirstlane(j));
                const int wj  = vj & 63;
                const int khj = ((vj >> 6) & 63) - row;
                const int cj  = vj >> 12;
                const int kw  = wj - lane;
                if (((unsigned)kw < 5u) & valid) {
                    if (cc < CAP)
                        outb[cc * NBINS + lane] = cj * 25 + khj * 5 + kw;
                    ++cc;
                }
            }
        }
        if (valid)
            for (int k = cc; k < CAP; ++k) outb[k * NBINS + lane] = -1;
    }
}

extern "C" void kernel_launch(void* const* d_in, const int* in_sizes, int n_in,
                              void* d_out, int out_size, void* d_ws, size_t ws_size,
                              hipStream_t stream) {
    const int* spikes = (const int*)d_in[0];  // (B, S, 1, 1) int32
    // d_in[1] (indices table) unused: membership is pure arithmetic.
    int* out = (int*)d_out;                   // (B, CAP, OH, OW) int32

    dim3 grid(OHh * NB);                      // 3840 blocks, batch-minor
    dim3 block(256);                          // 4 waves/block
    sort_spikes_row4<<<grid, block, 0, stream>>>(spikes, out);
}